// Round 1
// baseline (255.286 us; speedup 1.0000x reference)
//
#include <hip/hip_runtime.h>
#include <stdint.h>

typedef __bf16 bf16_t;
typedef __bf16 bf16x8 __attribute__((ext_vector_type(8)));
typedef float f32x4 __attribute__((ext_vector_type(4)));

#define LOG2E 1.44269504088896340736f

__device__ __forceinline__ float fexp2(float x) {
#if __has_builtin(__builtin_amdgcn_exp2f)
    return __builtin_amdgcn_exp2f(x);   // bare v_exp_f32
#else
    return exp2f(x);
#endif
}

// ---- async global->LDS, 16B per lane. LDS dest = wave-uniform base + lane*16.
__device__ __forceinline__ void gld_lds16(const bf16_t* g, bf16_t* l) {
    __builtin_amdgcn_global_load_lds(
        (__attribute__((address_space(1))) void*)(bf16_t*)g,
        (__attribute__((address_space(3))) void*)l,
        16, 0, 0);
}

// ============================ fused prep kernel ============================
// blocks [0,8192): x f32->bf16 | [8192,11264): W_qkv transpose | [11264,12288): W_o
__global__ __launch_bounds__(256) void prep_k(
    const float* __restrict__ x, bf16_t* __restrict__ xb,
    const float* __restrict__ Wqkv, bf16_t* __restrict__ wqkvT,
    const float* __restrict__ Wo, bf16_t* __restrict__ woT)
{
    __shared__ float t[32][33];
    const int tid = threadIdx.x;
    int blk = blockIdx.x;
    if (blk < 8192) {
        int i = blk * 1024 + tid * 4;
        float4 v = *(const float4*)(x + i);
        union { bf16_t b[4]; uint2 u; } u;
        u.b[0] = (bf16_t)v.x; u.b[1] = (bf16_t)v.y; u.b[2] = (bf16_t)v.z; u.b[3] = (bf16_t)v.w;
        *(uint2*)(xb + i) = u.u;
        return;
    }
    const float* in; bf16_t* out; int C, bx, by;
    if (blk < 11264) { blk -= 8192; in = Wqkv; out = wqkvT; C = 3072; bx = blk % 96; by = blk / 96; }
    else             { blk -= 11264; in = Wo;   out = woT;   C = 1024; bx = blk % 32; by = blk / 32; }
    const int R = 1024;
    const int tx = tid & 31, ty = tid >> 5;
    const int c0 = bx * 32, r0 = by * 32;
    #pragma unroll
    for (int j = 0; j < 32; j += 8)
        t[ty + j][tx] = in[(size_t)(r0 + ty + j) * C + c0 + tx];
    __syncthreads();
    #pragma unroll
    for (int j = 0; j < 32; j += 8)
        out[(size_t)(c0 + ty + j) * R + r0 + tx] = (bf16_t)t[tx][ty + j];
}

// ============================ 3-deep pipelined GEMM body ====================
// C[256x128] = A[m0:+256,:1024] * B[n0:+128,:1024]^T (both row-major, k-contig).
// 512 threads / 8 waves: wm=w>>1 (4 M-subtiles of 64), wn=w&1 (2 N-subtiles).
// 3-deep LDS pipeline (A: 3x32KB, B: 3x16KB = 144KB): stage tile t+2 at top of
// iter t; s_waitcnt vmcnt(6) (never 0 mid-loop) + raw s_barrier once per K-tile.
//   RAW: at iter-t end, outstanding <= 6(tile t+1)+6(tile t+2); vmcnt(6) => all
//        of tile t+1 (the oldest 6) landed before anyone reads it.
//   WAR: tile t+2 overwrites slot of tile t-1, whose reads completed before each
//        wave's MFMAs, which precede the iter-(t-1) barrier.
// XOR swizzle (proven): LDS chunk c of row r holds global chunk c^(r&7).
__device__ __forceinline__ void gemm_body_3deep(
    const bf16_t* __restrict__ A, const bf16_t* __restrict__ Bt,
    bf16_t* Al, bf16_t* Bl, f32x4 (&acc)[4][4], int m0, int n0)
{
    const int tid = threadIdx.x;
    const int w = tid >> 6, lane = tid & 63;
    const int l15 = lane & 15, quad = lane >> 4;
    const int wm = w >> 1, wn = w & 1;

    const int srow = lane >> 3;                 // 0..7 within an 8-row group
    const int scg = ((lane & 7) ^ srow) * 8;    // pre-swizzled global chunk
    const bf16_t* Ag = A  + (size_t)(m0 + w * 32 + srow) * 1024 + scg;
    const bf16_t* Bg = Bt + (size_t)(n0 + w * 16 + srow) * 1024 + scg;
    bf16_t* Ald = Al + (w * 32) * 64;           // wave's A staging base (slot 0)
    bf16_t* Bld = Bl + (w * 16) * 64;

    const int rc0 = (quad ^ (l15 & 7)) * 8;
    const int rc1 = ((quad + 4) ^ (l15 & 7)) * 8;

    auto stage = [&](int t, int s) {            // 6 x gld_lds16 per thread
        const int koff = t * 64;
        #pragma unroll
        for (int j = 0; j < 4; j++)
            gld_lds16(Ag + koff + (size_t)(j * 8) * 1024,
                      Ald + s * 16384 + (j * 8) * 64);
        #pragma unroll
        for (int j = 0; j < 2; j++)
            gld_lds16(Bg + koff + (size_t)(j * 8) * 1024,
                      Bld + s * 8192 + (j * 8) * 64);
    };

    // prologue: tiles 0,1 in flight; wait tile 0 (keep tile 1's 6 flying)
    stage(0, 0);
    stage(1, 1);
    asm volatile("s_waitcnt vmcnt(6)" ::: "memory");
    __builtin_amdgcn_s_barrier();

    int cur = 0, stg = 2;
    for (int t = 0; t < 16; ++t) {
        if (t < 14) stage(t + 2, stg);
        const bf16_t* Ab = Al + cur * 16384;
        const bf16_t* Bb = Bl + cur * 8192;
        #pragma unroll
        for (int hh = 0; hh < 2; hh++) {
            const int rc = hh ? rc1 : rc0;
            bf16x8 af[4], bfr[4];
            #pragma unroll
            for (int mi = 0; mi < 4; mi++)
                af[mi] = *(const bf16x8*)(Ab + (wm * 64 + mi * 16 + l15) * 64 + rc);
            #pragma unroll
            for (int ni = 0; ni < 4; ni++)
                bfr[ni] = *(const bf16x8*)(Bb + (wn * 64 + ni * 16 + l15) * 64 + rc);
            __builtin_amdgcn_s_setprio(1);
            #pragma unroll
            for (int mi = 0; mi < 4; mi++)
                #pragma unroll
                for (int ni = 0; ni < 4; ni++)
                    acc[mi][ni] = __builtin_amdgcn_mfma_f32_16x16x32_bf16(
                        af[mi], bfr[ni], acc[mi][ni], 0, 0, 0);
            __builtin_amdgcn_s_setprio(0);
        }
        if (t < 15) {
            if (t < 14) asm volatile("s_waitcnt vmcnt(6)" ::: "memory");
            else        asm volatile("s_waitcnt vmcnt(0)" ::: "memory");
            __builtin_amdgcn_s_barrier();
        }
        cur = (cur == 2) ? 0 : cur + 1;
        stg = (stg == 2) ? 0 : stg + 1;
    }
}

// ============================ GEMM1: qkv projection (A=W, B=x) ============
// m = weight col (0..3071), n = token row (0..8191). grid (64, 12) = 768 blocks
// = exactly 3 rounds of 256 CUs at 1 block/CU (144KB LDS).
__global__ __launch_bounds__(512) void gemm_qkv_k(
    const bf16_t* __restrict__ X, const bf16_t* __restrict__ WT,
    const float* __restrict__ bias,
    bf16_t* __restrict__ Qb, bf16_t* __restrict__ Kb, bf16_t* __restrict__ VTb)
{
    __shared__ bf16_t Al[3 * 256 * 64];   // 96 KB
    __shared__ bf16_t Bl[3 * 128 * 64];   // 48 KB
    const int tid = threadIdx.x;
    const int lane = tid & 63, w = tid >> 6;
    const int l15 = lane & 15, quad = lane >> 4;
    const int wm = w >> 1, wn = w & 1;
    const int n0 = blockIdx.x * 128;   // token rows
    const int m0 = blockIdx.y * 256;   // weight cols

    f32x4 acc[4][4];
    #pragma unroll
    for (int mi = 0; mi < 4; mi++)
        #pragma unroll
        for (int ni = 0; ni < 4; ni++) acc[mi][ni] = (f32x4){0.f, 0.f, 0.f, 0.f};

    gemm_body_3deep(WT, X, Al, Bl, acc, m0, n0);

    const float QSCALE = 0.125f * LOG2E;
    const int region = m0 >> 10;  // 0:Q 1:K 2:V (uniform per block; 256 | 1024)
    #pragma unroll
    for (int mi = 0; mi < 4; mi++) {
        const int mbase = m0 + wm * 64 + mi * 16 + quad * 4;
        const float4 bia = *(const float4*)(bias + mbase);
        const float ba[4] = {bia.x, bia.y, bia.z, bia.w};
        const int col = mbase & 1023;
        const int h = col >> 6, dbase = col & 63;
        #pragma unroll
        for (int ni = 0; ni < 4; ni++) {
            const int n = n0 + wn * 64 + ni * 16 + l15;
            const int b = n >> 11, s = n & 2047;
            if (region == 0) {
                union { bf16_t bv[4]; uint2 u; } u;
                #pragma unroll
                for (int r = 0; r < 4; r++)
                    u.bv[r] = (bf16_t)((acc[mi][ni][r] + ba[r]) * QSCALE);
                *(uint2*)(Qb + (((size_t)b * 16 + h) * 2048 + s) * 64 + dbase) = u.u;
            } else if (region == 1) {
                union { bf16_t bv[4]; uint2 u; } u;
                #pragma unroll
                for (int r = 0; r < 4; r++)
                    u.bv[r] = (bf16_t)(acc[mi][ni][r] + ba[r]);
                *(uint2*)(Kb + (((size_t)b * 16 + h) * 2048 + s) * 64 + dbase) = u.u;
            } else {
                bf16_t* dst = VTb + (((size_t)b * 16 + h) * 64 + dbase) * 2048 + s;
                #pragma unroll
                for (int r = 0; r < 4; r++)
                    dst[(size_t)r * 2048] = (bf16_t)(acc[mi][ni][r] + ba[r]);
            }
        }
    }
}

// ============================ flash attention (S^T form) ====================
// R4-PROVEN VERSION (64-q blocks, grid 2048) — unchanged this round.
__global__ __launch_bounds__(256) void attn_k(
    const bf16_t* __restrict__ Qb, const bf16_t* __restrict__ Kb,
    const bf16_t* __restrict__ VTb, bf16_t* __restrict__ Ob)
{
    __shared__ bf16_t Kl[64 * 64];     // [kv][d], swizzled
    __shared__ bf16_t Vl[64 * 64];     // [d][kv], swizzled
    __shared__ bf16_t Pl[4][16 * 72];  // per-wave P[q][kv], stride 72

    const int tid = threadIdx.x;
    const int w = tid >> 6, lane = tid & 63;
    const int l15 = lane & 15, quad = lane >> 4;
    const int idx = blockIdx.x;
    const int qt = 31 - (idx >> 6);    // longest first
    const int bh = idx & 63;
    const int b = bh >> 4, h = bh & 15;
    const int q0 = qt * 64;

    const bf16_t* Qp = Qb + (size_t)bh * 2048 * 64;
    const bf16_t* Kp = Kb + (size_t)bh * 2048 * 64;
    const bf16_t* Vp = VTb + (size_t)bh * 64 * 2048;

    const int srow = w * 16 + (lane >> 3);
    const int scol = ((lane & 7) ^ ((lane >> 3) & 7)) * 8;
    const int rc0 = (quad ^ (l15 & 7)) * 8;
    const int rc1 = ((quad + 4) ^ (l15 & 7)) * 8;

    // Q as B-frag: rows q = q0+16w+l15, d-contig
    const int qrow = q0 + w * 16 + l15;
    bf16x8 aq0 = *(const bf16x8*)(Qp + (size_t)qrow * 64 + quad * 8);
    bf16x8 aq1 = *(const bf16x8*)(Qp + (size_t)qrow * 64 + 32 + quad * 8);

    bf16x8 vone;
    #pragma unroll
    for (int j = 0; j < 8; j++) vone[j] = (bf16_t)1.0f;

    f32x4 o[4];   // O^T: col(l15)=q, row(quad*4+r)=d within chunk ni
    #pragma unroll
    for (int ni = 0; ni < 4; ni++) o[ni] = (f32x4){0.f, 0.f, 0.f, 0.f};
    f32x4 lacc = (f32x4){0.f, 0.f, 0.f, 0.f};
    const int qloc = w * 16 + l15;     // q - q0, lane-uniform over regs

    for (int kv0 = 0; kv0 <= q0; kv0 += 64) {
        __syncthreads();
        gld_lds16(Kp + (size_t)(kv0 + srow) * 64 + scol, Kl + (w * 16) * 64);
        gld_lds16(Kp + (size_t)(kv0 + srow + 8) * 64 + scol, Kl + (w * 16 + 8) * 64);
        gld_lds16(Vp + (size_t)srow * 2048 + kv0 + scol, Vl + (w * 16) * 64);
        gld_lds16(Vp + (size_t)(srow + 8) * 2048 + kv0 + scol, Vl + (w * 16 + 8) * 64);
        __syncthreads();

        // S^T chunk ni: rows kv = kv0+ni*16+quad*4+r, cols q
        f32x4 sv[4];
        #pragma unroll
        for (int ni = 0; ni < 4; ni++) {
            bf16x8 ak0 = *(const bf16x8*)(Kl + (ni * 16 + l15) * 64 + rc0);
            bf16x8 ak1 = *(const bf16x8*)(Kl + (ni * 16 + l15) * 64 + rc1);
            f32x4 z = (f32x4){0.f, 0.f, 0.f, 0.f};
            z = __builtin_amdgcn_mfma_f32_16x16x32_bf16(ak0, aq0, z, 0, 0, 0);
            z = __builtin_amdgcn_mfma_f32_16x16x32_bf16(ak1, aq1, z, 0, 0, 0);
            sv[ni] = z;
        }

        if (kv0 == q0) {  // causal mask, diagonal tile only: kv > q
            #pragma unroll
            for (int ni = 0; ni < 4; ni++)
                #pragma unroll
                for (int r = 0; r < 4; r++)
                    if (ni * 16 + quad * 4 + r > qloc) sv[ni][r] = -INFINITY;
        }

        // p = exp2(s), pack 4 kv-adjacent -> one 8B LDS write per chunk
        #pragma unroll
        for (int ni = 0; ni < 4; ni++) {
            union { bf16_t bv[4]; uint2 u; } pk;
            #pragma unroll
            for (int r = 0; r < 4; r++) pk.bv[r] = (bf16_t)fexp2(sv[ni][r]);
            *(uint2*)(&Pl[w][l15 * 72 + ni * 16 + quad * 4]) = pk.u;
        }
        // no barrier: Pl[w] wave-private, same-wave DS ops ordered

        // P as B-frag: rows q=l15, kv-contig
        bf16x8 pa0 = *(const bf16x8*)(&Pl[w][l15 * 72 + quad * 8]);
        bf16x8 pa1 = *(const bf16x8*)(&Pl[w][l15 * 72 + 32 + quad * 8]);
        #pragma unroll
        for (int ni = 0; ni < 4; ni++) {
            bf16x8 bv0 = *(const bf16x8*)(Vl + (ni * 16 + l15) * 64 + rc0);
            bf16x8 bv1 = *(const bf16x8*)(Vl + (ni * 16 + l15) * 64 + rc1);
            o[ni] = __builtin_amdgcn_mfma_f32_16x16x32_bf16(bv0, pa0, o[ni], 0, 0, 0);
            o[ni] = __builtin_amdgcn_mfma_f32_16x16x32_bf16(bv1, pa1, o[ni], 0, 0, 0);
        }
        // row-sum: ones x P -> every reg holds sum_kv P[q=l15][kv]
        lacc = __builtin_amdgcn_mfma_f32_16x16x32_bf16(vone, pa0, lacc, 0, 0, 0);
        lacc = __builtin_amdgcn_mfma_f32_16x16x32_bf16(vone, pa1, lacc, 0, 0, 0);
    }

    const float inv = 1.0f / lacc[0];
    const int s = q0 + w * 16 + l15;
    bf16_t* obase = Ob + ((size_t)b * 2048 + s) * 1024 + h * 64;
    #pragma unroll
    for (int ni = 0; ni < 4; ni++) {
        union { bf16_t bv[4]; uint2 u; } u;
        #pragma unroll
        for (int r = 0; r < 4; r++) u.bv[r] = (bf16_t)(o[ni][r] * inv);
        *(uint2*)(obase + ni * 16 + quad * 4) = u.u;
    }
}

// ============================ GEMM2: output projection (A=Wo, B=O) =========
// grid (64, 4) = 256 blocks = exactly 1 round of 256 CUs.
__global__ __launch_bounds__(512) void gemm_out_k(
    const bf16_t* __restrict__ O, const bf16_t* __restrict__ WT,
    const float* __restrict__ bias, float* __restrict__ out)
{
    __shared__ bf16_t Al[3 * 256 * 64];   // 96 KB
    __shared__ bf16_t Bl[3 * 128 * 64];   // 48 KB
    const int tid = threadIdx.x;
    const int lane = tid & 63, w = tid >> 6;
    const int l15 = lane & 15, quad = lane >> 4;
    const int wm = w >> 1, wn = w & 1;
    const int n0 = blockIdx.x * 128;   // token rows
    const int m0 = blockIdx.y * 256;   // out cols

    f32x4 acc[4][4];
    #pragma unroll
    for (int mi = 0; mi < 4; mi++)
        #pragma unroll
        for (int ni = 0; ni < 4; ni++) acc[mi][ni] = (f32x4){0.f, 0.f, 0.f, 0.f};

    gemm_body_3deep(WT, O, Al, Bl, acc, m0, n0);

    #pragma unroll
    for (int mi = 0; mi < 4; mi++) {
        const int mbase = m0 + wm * 64 + mi * 16 + quad * 4;
        const float4 bia = *(const float4*)(bias + mbase);
        #pragma unroll
        for (int ni = 0; ni < 4; ni++) {
            const int n = n0 + wn * 64 + ni * 16 + l15;
            float4 v;
            v.x = acc[mi][ni][0] + bia.x;
            v.y = acc[mi][ni][1] + bia.y;
            v.z = acc[mi][ni][2] + bia.z;
            v.w = acc[mi][ni][3] + bia.w;
            *(float4*)(out + (size_t)n * 1024 + mbase) = v;
        }
    }
}

// ============================ launcher ============================

extern "C" void kernel_launch(void* const* d_in, const int* in_sizes, int n_in,
                              void* d_out, int out_size, void* d_ws, size_t ws_size,
                              hipStream_t stream) {
    const float* x     = (const float*)d_in[0];
    const float* W_qkv = (const float*)d_in[1];
    const float* b_qkv = (const float*)d_in[2];
    const float* W_o   = (const float*)d_in[3];
    const float* b_o   = (const float*)d_in[4];
    float* out = (float*)d_out;

    char* ws = (char*)d_ws;
    size_t off = 0;
    auto alloc = [&](size_t bytes) -> void* {
        void* p = ws + off;
        off += (bytes + 255) & ~(size_t)255;
        return p;
    };
    bf16_t* xb    = (bf16_t*)alloc((size_t)8192 * 1024 * 2);
    bf16_t* wqkvT = (bf16_t*)alloc((size_t)3072 * 1024 * 2);
    bf16_t* woT   = (bf16_t*)alloc((size_t)1024 * 1024 * 2);
    bf16_t* Qb    = (bf16_t*)alloc((size_t)8192 * 1024 * 2);
    bf16_t* Kb    = (bf16_t*)alloc((size_t)8192 * 1024 * 2);
    bf16_t* VTb   = (bf16_t*)alloc((size_t)8192 * 1024 * 2);
    bf16_t* Ob    = xb;  // xb dead after gemm_qkv_k

    prep_k<<<12288, 256, 0, stream>>>(x, xb, W_qkv, wqkvT, W_o, woT);
    gemm_qkv_k<<<dim3(64, 12), 512, 0, stream>>>(xb, wqkvT, b_qkv, Qb, Kb, VTb);
    attn_k<<<2048, 256, 0, stream>>>(Qb, Kb, VTb, Ob);
    gemm_out_k<<<dim3(64, 4), 512, 0, stream>>>(Ob, woT, b_o, out);
}

// Round 2
// 237.448 us; speedup vs baseline: 1.0751x; 1.0751x over previous
//
#include <hip/hip_runtime.h>
#include <stdint.h>

typedef __bf16 bf16_t;
typedef __bf16 bf16x8 __attribute__((ext_vector_type(8)));
typedef float f32x4 __attribute__((ext_vector_type(4)));

#define LOG2E 1.44269504088896340736f

__device__ __forceinline__ float fexp2(float x) {
#if __has_builtin(__builtin_amdgcn_exp2f)
    return __builtin_amdgcn_exp2f(x);   // bare v_exp_f32
#else
    return exp2f(x);
#endif
}

// ---- async global->LDS, 16B per lane. LDS dest = wave-uniform base + lane*16.
__device__ __forceinline__ void gld_lds16(const bf16_t* g, bf16_t* l) {
    __builtin_amdgcn_global_load_lds(
        (__attribute__((address_space(1))) void*)(bf16_t*)g,
        (__attribute__((address_space(3))) void*)l,
        16, 0, 0);
}

// ============================ fused prep kernel ============================
// blocks [0,8192): x f32->bf16 | [8192,11264): W_qkv transpose | [11264,12288): W_o
__global__ __launch_bounds__(256) void prep_k(
    const float* __restrict__ x, bf16_t* __restrict__ xb,
    const float* __restrict__ Wqkv, bf16_t* __restrict__ wqkvT,
    const float* __restrict__ Wo, bf16_t* __restrict__ woT)
{
    __shared__ float t[32][33];
    const int tid = threadIdx.x;
    int blk = blockIdx.x;
    if (blk < 8192) {
        int i = blk * 1024 + tid * 4;
        float4 v = *(const float4*)(x + i);
        union { bf16_t b[4]; uint2 u; } u;
        u.b[0] = (bf16_t)v.x; u.b[1] = (bf16_t)v.y; u.b[2] = (bf16_t)v.z; u.b[3] = (bf16_t)v.w;
        *(uint2*)(xb + i) = u.u;
        return;
    }
    const float* in; bf16_t* out; int C, bx, by;
    if (blk < 11264) { blk -= 8192; in = Wqkv; out = wqkvT; C = 3072; bx = blk % 96; by = blk / 96; }
    else             { blk -= 11264; in = Wo;   out = woT;   C = 1024; bx = blk % 32; by = blk / 32; }
    const int R = 1024;
    const int tx = tid & 31, ty = tid >> 5;
    const int c0 = bx * 32, r0 = by * 32;
    #pragma unroll
    for (int j = 0; j < 32; j += 8)
        t[ty + j][tx] = in[(size_t)(r0 + ty + j) * C + c0 + tx];
    __syncthreads();
    #pragma unroll
    for (int j = 0; j < 32; j += 8)
        out[(size_t)(c0 + ty + j) * R + r0 + tx] = (bf16_t)t[tx][ty + j];
}

// ================= m201-style fine-phase pipelined GEMM body =================
// C[128x256] = A[m0:+128,:1024] * B[n0:+256,:1024]^T (row-major, k-contig).
// 512 thr / 8 waves, 2M x 4N, per-wave 64x64 (proven frag math: acc[4][4],
// C col(l15)=n, row(quad*4+r)=m). BK=64; K=1024 -> 16 K-tiles.
// 3 LDS slots x (A 16KB + B 32KB) = 144 KB; prefetch distance 2 K-tiles.
// Per K-tile: 2 phases (k-half). Phase = {8 ds_read_b128 (early) | 3 gld_lds |
// [vmcnt(6) odd phase] | s_barrier | setprio(1) 16 MFMA setprio(0) | s_barrier}.
// vmcnt(6) at (t,h1): outstanding = batches (t,h0)+(t,h1) = 6 -> everything
// through (t-1,h1) landed = K-tile t+1 fully staged; barrier publishes.
// WAR: stage into slot (t+2)%3=(t-1)%3 issues after B2(t-1,h1), after all
// reads of that slot completed (lgkmcnt before MFMA before barrier).
// XOR swizzle (proven, conflict-free): LDS chunk c of row r = global chunk c^(r&7).
__device__ __forceinline__ void gemm_body_pipe(
    const bf16_t* __restrict__ A, const bf16_t* __restrict__ Bt,
    bf16_t* Al, bf16_t* Bl, f32x4 (&acc)[4][4], int m0, int n0)
{
    const int tid = threadIdx.x;
    const int w = tid >> 6, lane = tid & 63;
    const int l15 = lane & 15, quad = lane >> 4;
    const int wm = w >> 2, wn = w & 3;

    const int srow = lane >> 3;                 // 0..7 within an 8-row group
    const int scg = ((lane & 7) ^ srow) * 8;    // pre-swizzled global chunk
    const bf16_t* Ag = A  + (size_t)(m0 + w * 16 + srow) * 1024 + scg;
    const bf16_t* Bg = Bt + (size_t)(n0 + w * 32 + srow) * 1024 + scg;

    const int rc0 = (quad ^ (l15 & 7)) * 8;
    const int rc1 = ((quad + 4) ^ (l15 & 7)) * 8;

    // slot strides (elements): A 128*64=8192, B 256*64=16384
    auto stage0 = [&](int kt, int ss) {   // A j0, A j1, B j0
        gld_lds16(Ag + kt * 64,                       Al + ss * 8192  + (w * 16) * 64);
        gld_lds16(Ag + kt * 64 + (size_t)8 * 1024,    Al + ss * 8192  + (w * 16 + 8) * 64);
        gld_lds16(Bg + kt * 64,                       Bl + ss * 16384 + (w * 32) * 64);
    };
    auto stage1 = [&](int kt, int ss) {   // B j1, B j2, B j3
        gld_lds16(Bg + kt * 64 + (size_t)8 * 1024,    Bl + ss * 16384 + (w * 32 + 8) * 64);
        gld_lds16(Bg + kt * 64 + (size_t)16 * 1024,   Bl + ss * 16384 + (w * 32 + 16) * 64);
        gld_lds16(Bg + kt * 64 + (size_t)24 * 1024,   Bl + ss * 16384 + (w * 32 + 24) * 64);
    };

    // prologue: K-tiles 0,1 fully issued; confirm kt0 (kt1's 6 stay in flight)
    stage0(0, 0); stage1(0, 0);
    stage0(1, 1); stage1(1, 1);
    asm volatile("s_waitcnt vmcnt(6)" ::: "memory");
    __builtin_amdgcn_s_barrier();

    int cs = 0, ss = 2;
    for (int t = 0; t < 16; ++t) {
        const bf16_t* Ab = Al + cs * 8192;
        const bf16_t* Bb = Bl + cs * 16384;

        // ---------------- phase h=0 (k 0..31 of this K-tile) ----------------
        {
            bf16x8 af[4], bfr[4];
            #pragma unroll
            for (int mi = 0; mi < 4; mi++)
                af[mi] = *(const bf16x8*)(Ab + (wm * 64 + mi * 16 + l15) * 64 + rc0);
            #pragma unroll
            for (int ni = 0; ni < 4; ni++)
                bfr[ni] = *(const bf16x8*)(Bb + (wn * 64 + ni * 16 + l15) * 64 + rc0);
            if (t < 14) stage0(t + 2, ss);
            __builtin_amdgcn_s_barrier();
            __builtin_amdgcn_s_setprio(1);
            #pragma unroll
            for (int mi = 0; mi < 4; mi++)
                #pragma unroll
                for (int ni = 0; ni < 4; ni++)
                    acc[mi][ni] = __builtin_amdgcn_mfma_f32_16x16x32_bf16(
                        af[mi], bfr[ni], acc[mi][ni], 0, 0, 0);
            __builtin_amdgcn_s_setprio(0);
            __builtin_amdgcn_s_barrier();
        }

        // ---------------- phase h=1 (k 32..63 of this K-tile) ----------------
        {
            bf16x8 af[4], bfr[4];
            #pragma unroll
            for (int mi = 0; mi < 4; mi++)
                af[mi] = *(const bf16x8*)(Ab + (wm * 64 + mi * 16 + l15) * 64 + rc1);
            #pragma unroll
            for (int ni = 0; ni < 4; ni++)
                bfr[ni] = *(const bf16x8*)(Bb + (wn * 64 + ni * 16 + l15) * 64 + rc1);
            if (t < 14) {
                stage1(t + 2, ss);
                asm volatile("s_waitcnt vmcnt(6)" ::: "memory");  // confirm kt t+1
            } else if (t == 14) {
                asm volatile("s_waitcnt vmcnt(0)" ::: "memory");  // confirm kt 15 (tail)
            }
            __builtin_amdgcn_s_barrier();
            __builtin_amdgcn_s_setprio(1);
            #pragma unroll
            for (int mi = 0; mi < 4; mi++)
                #pragma unroll
                for (int ni = 0; ni < 4; ni++)
                    acc[mi][ni] = __builtin_amdgcn_mfma_f32_16x16x32_bf16(
                        af[mi], bfr[ni], acc[mi][ni], 0, 0, 0);
            __builtin_amdgcn_s_setprio(0);
            __builtin_amdgcn_s_barrier();
        }

        cs = (cs == 2) ? 0 : cs + 1;
        ss = (ss == 2) ? 0 : ss + 1;
    }
}

// ============================ GEMM1: qkv projection (A=W, B=x) ============
// m = weight col (0..3071), n = token row (0..8191). grid (32, 24) = 768 blocks
// = exactly 3 rounds of 256 CUs at 1 block/CU (144 KB LDS).
__global__ __launch_bounds__(512) void gemm_qkv_k(
    const bf16_t* __restrict__ X, const bf16_t* __restrict__ WT,
    const float* __restrict__ bias,
    bf16_t* __restrict__ Qb, bf16_t* __restrict__ Kb, bf16_t* __restrict__ VTb)
{
    __shared__ bf16_t Al[3 * 128 * 64];   // 48 KB
    __shared__ bf16_t Bl[3 * 256 * 64];   // 96 KB
    const int tid = threadIdx.x;
    const int lane = tid & 63, w = tid >> 6;
    const int l15 = lane & 15, quad = lane >> 4;
    const int wm = w >> 2, wn = w & 3;
    const int n0 = blockIdx.x * 256;   // token rows
    const int m0 = blockIdx.y * 128;   // weight cols

    f32x4 acc[4][4];
    #pragma unroll
    for (int mi = 0; mi < 4; mi++)
        #pragma unroll
        for (int ni = 0; ni < 4; ni++) acc[mi][ni] = (f32x4){0.f, 0.f, 0.f, 0.f};

    gemm_body_pipe(WT, X, Al, Bl, acc, m0, n0);

    const float QSCALE = 0.125f * LOG2E;
    const int region = m0 >> 10;  // 0:Q 1:K 2:V (uniform per block; 128 | 1024)
    #pragma unroll
    for (int mi = 0; mi < 4; mi++) {
        const int mbase = m0 + wm * 64 + mi * 16 + quad * 4;
        const float4 bia = *(const float4*)(bias + mbase);
        const float ba[4] = {bia.x, bia.y, bia.z, bia.w};
        const int col = mbase & 1023;
        const int h = col >> 6, dbase = col & 63;
        #pragma unroll
        for (int ni = 0; ni < 4; ni++) {
            const int n = n0 + wn * 64 + ni * 16 + l15;
            const int b = n >> 11, s = n & 2047;
            if (region == 0) {
                union { bf16_t bv[4]; uint2 u; } u;
                #pragma unroll
                for (int r = 0; r < 4; r++)
                    u.bv[r] = (bf16_t)((acc[mi][ni][r] + ba[r]) * QSCALE);
                *(uint2*)(Qb + (((size_t)b * 16 + h) * 2048 + s) * 64 + dbase) = u.u;
            } else if (region == 1) {
                union { bf16_t bv[4]; uint2 u; } u;
                #pragma unroll
                for (int r = 0; r < 4; r++)
                    u.bv[r] = (bf16_t)(acc[mi][ni][r] + ba[r]);
                *(uint2*)(Kb + (((size_t)b * 16 + h) * 2048 + s) * 64 + dbase) = u.u;
            } else {
                bf16_t* dst = VTb + (((size_t)b * 16 + h) * 64 + dbase) * 2048 + s;
                #pragma unroll
                for (int r = 0; r < 4; r++)
                    dst[(size_t)r * 2048] = (bf16_t)(acc[mi][ni][r] + ba[r]);
            }
        }
    }
}

// ============================ flash attention (S^T form) ====================
// R4-PROVEN VERSION (64-q blocks, grid 2048) — unchanged this round.
__global__ __launch_bounds__(256) void attn_k(
    const bf16_t* __restrict__ Qb, const bf16_t* __restrict__ Kb,
    const bf16_t* __restrict__ VTb, bf16_t* __restrict__ Ob)
{
    __shared__ bf16_t Kl[64 * 64];     // [kv][d], swizzled
    __shared__ bf16_t Vl[64 * 64];     // [d][kv], swizzled
    __shared__ bf16_t Pl[4][16 * 72];  // per-wave P[q][kv], stride 72

    const int tid = threadIdx.x;
    const int w = tid >> 6, lane = tid & 63;
    const int l15 = lane & 15, quad = lane >> 4;
    const int idx = blockIdx.x;
    const int qt = 31 - (idx >> 6);    // longest first
    const int bh = idx & 63;
    const int b = bh >> 4, h = bh & 15;
    const int q0 = qt * 64;

    const bf16_t* Qp = Qb + (size_t)bh * 2048 * 64;
    const bf16_t* Kp = Kb + (size_t)bh * 2048 * 64;
    const bf16_t* Vp = VTb + (size_t)bh * 64 * 2048;

    const int srow = w * 16 + (lane >> 3);
    const int scol = ((lane & 7) ^ ((lane >> 3) & 7)) * 8;
    const int rc0 = (quad ^ (l15 & 7)) * 8;
    const int rc1 = ((quad + 4) ^ (l15 & 7)) * 8;

    // Q as B-frag: rows q = q0+16w+l15, d-contig
    const int qrow = q0 + w * 16 + l15;
    bf16x8 aq0 = *(const bf16x8*)(Qp + (size_t)qrow * 64 + quad * 8);
    bf16x8 aq1 = *(const bf16x8*)(Qp + (size_t)qrow * 64 + 32 + quad * 8);

    bf16x8 vone;
    #pragma unroll
    for (int j = 0; j < 8; j++) vone[j] = (bf16_t)1.0f;

    f32x4 o[4];   // O^T: col(l15)=q, row(quad*4+r)=d within chunk ni
    #pragma unroll
    for (int ni = 0; ni < 4; ni++) o[ni] = (f32x4){0.f, 0.f, 0.f, 0.f};
    f32x4 lacc = (f32x4){0.f, 0.f, 0.f, 0.f};
    const int qloc = w * 16 + l15;     // q - q0, lane-uniform over regs

    for (int kv0 = 0; kv0 <= q0; kv0 += 64) {
        __syncthreads();
        gld_lds16(Kp + (size_t)(kv0 + srow) * 64 + scol, Kl + (w * 16) * 64);
        gld_lds16(Kp + (size_t)(kv0 + srow + 8) * 64 + scol, Kl + (w * 16 + 8) * 64);
        gld_lds16(Vp + (size_t)srow * 2048 + kv0 + scol, Vl + (w * 16) * 64);
        gld_lds16(Vp + (size_t)(srow + 8) * 2048 + kv0 + scol, Vl + (w * 16 + 8) * 64);
        __syncthreads();

        // S^T chunk ni: rows kv = kv0+ni*16+quad*4+r, cols q
        f32x4 sv[4];
        #pragma unroll
        for (int ni = 0; ni < 4; ni++) {
            bf16x8 ak0 = *(const bf16x8*)(Kl + (ni * 16 + l15) * 64 + rc0);
            bf16x8 ak1 = *(const bf16x8*)(Kl + (ni * 16 + l15) * 64 + rc1);
            f32x4 z = (f32x4){0.f, 0.f, 0.f, 0.f};
            z = __builtin_amdgcn_mfma_f32_16x16x32_bf16(ak0, aq0, z, 0, 0, 0);
            z = __builtin_amdgcn_mfma_f32_16x16x32_bf16(ak1, aq1, z, 0, 0, 0);
            sv[ni] = z;
        }

        if (kv0 == q0) {  // causal mask, diagonal tile only: kv > q
            #pragma unroll
            for (int ni = 0; ni < 4; ni++)
                #pragma unroll
                for (int r = 0; r < 4; r++)
                    if (ni * 16 + quad * 4 + r > qloc) sv[ni][r] = -INFINITY;
        }

        // p = exp2(s), pack 4 kv-adjacent -> one 8B LDS write per chunk
        #pragma unroll
        for (int ni = 0; ni < 4; ni++) {
            union { bf16_t bv[4]; uint2 u; } pk;
            #pragma unroll
            for (int r = 0; r < 4; r++) pk.bv[r] = (bf16_t)fexp2(sv[ni][r]);
            *(uint2*)(&Pl[w][l15 * 72 + ni * 16 + quad * 4]) = pk.u;
        }
        // no barrier: Pl[w] wave-private, same-wave DS ops ordered

        // P as B-frag: rows q=l15, kv-contig
        bf16x8 pa0 = *(const bf16x8*)(&Pl[w][l15 * 72 + quad * 8]);
        bf16x8 pa1 = *(const bf16x8*)(&Pl[w][l15 * 72 + 32 + quad * 8]);
        #pragma unroll
        for (int ni = 0; ni < 4; ni++) {
            bf16x8 bv0 = *(const bf16x8*)(Vl + (ni * 16 + l15) * 64 + rc0);
            bf16x8 bv1 = *(const bf16x8*)(Vl + (ni * 16 + l15) * 64 + rc1);
            o[ni] = __builtin_amdgcn_mfma_f32_16x16x32_bf16(bv0, pa0, o[ni], 0, 0, 0);
            o[ni] = __builtin_amdgcn_mfma_f32_16x16x32_bf16(bv1, pa1, o[ni], 0, 0, 0);
        }
        // row-sum: ones x P -> every reg holds sum_kv P[q=l15][kv]
        lacc = __builtin_amdgcn_mfma_f32_16x16x32_bf16(vone, pa0, lacc, 0, 0, 0);
        lacc = __builtin_amdgcn_mfma_f32_16x16x32_bf16(vone, pa1, lacc, 0, 0, 0);
    }

    const float inv = 1.0f / lacc[0];
    const int s = q0 + w * 16 + l15;
    bf16_t* obase = Ob + ((size_t)b * 2048 + s) * 1024 + h * 64;
    #pragma unroll
    for (int ni = 0; ni < 4; ni++) {
        union { bf16_t bv[4]; uint2 u; } u;
        #pragma unroll
        for (int r = 0; r < 4; r++) u.bv[r] = (bf16_t)(o[ni][r] * inv);
        *(uint2*)(obase + ni * 16 + quad * 4) = u.u;
    }
}

// ============================ GEMM2: output projection (A=Wo, B=O) =========
// grid (32, 4*2)= (32,8) = 256 blocks = exactly 1 round of 256 CUs.
__global__ __launch_bounds__(512) void gemm_out_k(
    const bf16_t* __restrict__ O, const bf16_t* __restrict__ WT,
    const float* __restrict__ bias, float* __restrict__ out)
{
    __shared__ bf16_t Al[3 * 128 * 64];   // 48 KB
    __shared__ bf16_t Bl[3 * 256 * 64];   // 96 KB
    const int tid = threadIdx.x;
    const int lane = tid & 63, w = tid >> 6;
    const int l15 = lane & 15, quad = lane >> 4;
    const int wm = w >> 2, wn = w & 3;
    const int n0 = blockIdx.x * 256;   // token rows
    const int m0 = blockIdx.y * 128;   // out cols

    f32x4 acc[4][4];
    #pragma unroll
    for (int mi = 0; mi < 4; mi++)
        #pragma unroll
        for (int ni = 0; ni < 4; ni++) acc[mi][ni] = (f32x4){0.f, 0.f, 0.f, 0.f};

    gemm_body_pipe(WT, O, Al, Bl, acc, m0, n0);

    #pragma unroll
    for (int mi = 0; mi < 4; mi++) {
        const int mbase = m0 + wm * 64 + mi * 16 + quad * 4;
        const float4 bia = *(const float4*)(bias + mbase);
        #pragma unroll
        for (int ni = 0; ni < 4; ni++) {
            const int n = n0 + wn * 64 + ni * 16 + l15;
            float4 v;
            v.x = acc[mi][ni][0] + bia.x;
            v.y = acc[mi][ni][1] + bia.y;
            v.z = acc[mi][ni][2] + bia.z;
            v.w = acc[mi][ni][3] + bia.w;
            *(float4*)(out + (size_t)n * 1024 + mbase) = v;
        }
    }
}

// ============================ launcher ============================

extern "C" void kernel_launch(void* const* d_in, const int* in_sizes, int n_in,
                              void* d_out, int out_size, void* d_ws, size_t ws_size,
                              hipStream_t stream) {
    const float* x     = (const float*)d_in[0];
    const float* W_qkv = (const float*)d_in[1];
    const float* b_qkv = (const float*)d_in[2];
    const float* W_o   = (const float*)d_in[3];
    const float* b_o   = (const float*)d_in[4];
    float* out = (float*)d_out;

    char* ws = (char*)d_ws;
    size_t off = 0;
    auto alloc = [&](size_t bytes) -> void* {
        void* p = ws + off;
        off += (bytes + 255) & ~(size_t)255;
        return p;
    };
    bf16_t* xb    = (bf16_t*)alloc((size_t)8192 * 1024 * 2);
    bf16_t* wqkvT = (bf16_t*)alloc((size_t)3072 * 1024 * 2);
    bf16_t* woT   = (bf16_t*)alloc((size_t)1024 * 1024 * 2);
    bf16_t* Qb    = (bf16_t*)alloc((size_t)8192 * 1024 * 2);
    bf16_t* Kb    = (bf16_t*)alloc((size_t)8192 * 1024 * 2);
    bf16_t* VTb   = (bf16_t*)alloc((size_t)8192 * 1024 * 2);
    bf16_t* Ob    = xb;  // xb dead after gemm_qkv_k

    prep_k<<<12288, 256, 0, stream>>>(x, xb, W_qkv, wqkvT, W_o, woT);
    gemm_qkv_k<<<dim3(32, 24), 512, 0, stream>>>(xb, wqkvT, b_qkv, Qb, Kb, VTb);
    attn_k<<<2048, 256, 0, stream>>>(Qb, Kb, VTb, Ob);
    gemm_out_k<<<dim3(32, 8), 512, 0, stream>>>(Ob, woT, b_o, out);
}